// Round 12
// baseline (544.942 us; speedup 1.0000x reference)
//
#include <hip/hip_runtime.h>
#include <math.h>

typedef __attribute__((ext_vector_type(8))) short short8;
typedef __attribute__((ext_vector_type(4))) float f32x4;
typedef unsigned short u16;
typedef unsigned int u32;

__device__ inline u16 f2b(float f) {  // f32 -> bf16 round-to-nearest-even
  u32 u = __float_as_uint(f);
  return (u16)((u + 0x7FFFu + ((u >> 16) & 1u)) >> 16);
}
__device__ inline float b2f(u16 b) { return __uint_as_float((u32)b << 16); }
__device__ inline float lrelu(float v) { return v > 0.f ? v : 0.2f * v; }

__device__ inline void gld_lds16(const void* g, void* l) {
  __builtin_amdgcn_global_load_lds((const __attribute__((address_space(1))) void*)g,
                                   (__attribute__((address_space(3))) void*)l, 16, 0, 0);
}

// ---------------- fused prep: casts (x, W1, W2, W3) + deg_count ----------------
__global__ void fused_prep(const float* __restrict__ x, u16* __restrict__ xb, int NX,
                           const float* __restrict__ W1, u16* __restrict__ Wt1,
                           const float* __restrict__ W2, u16* __restrict__ Wt2,
                           const float* __restrict__ W3, u16* __restrict__ Wt3,
                           const int* __restrict__ ei, int E0, int ET,
                           int* __restrict__ deg) {
  int i = blockIdx.x * blockDim.x + threadIdx.x;
  if (i < NX) {
    xb[i] = f2b(x[i]);
    return;
  }
  i -= NX;
  if (i < 64 * 512) {
    int k = i / 512, n = i % 512;
    Wt1[n * 64 + k] = f2b(W1[i]);
    return;
  }
  i -= 64 * 512;
  if (i < 512 * 512) {
    int k = i / 512, n = i % 512;
    Wt2[n * 512 + k] = f2b(W2[i]);
    return;
  }
  i -= 512 * 512;
  if (i < 512 * 128) {
    int k = i / 128, n = i % 128;
    Wt3[n * 512 + k] = f2b(W3[i]);
    return;
  }
  i -= 512 * 128;
  if (i < ET) {
    int d = (i < E0) ? ei[E0 + i] : (i - E0);
    atomicAdd(&deg[d], 1);
  }
}

// ---------------- bf16 MFMA GEMM with fused alpha epilogue, XCD-swizzled 1-D grid ----
// nStrips==4: linear id l -> xcd=l&7, k=l>>3, n=k&3, m=xcd+8*(k>>2); the 4 n-strips
// of an m-tile are ids spaced by 8 => same XCD => A-tile fetched once per XCD L2.
__global__ __launch_bounds__(256) void gemm_bf16_gat(
    const u16* __restrict__ A, const u16* __restrict__ Bt, u16* __restrict__ Hb,
    const float* __restrict__ a_src, const float* __restrict__ a_dst,
    float* __restrict__ aS, float* __restrict__ aD, int M, int HC, int K, int Hh,
    int gy, int nStrips) {
  int mIdx, nIdx;
  if (nStrips == 4) {
    int l = blockIdx.x;
    int xcd = l & 7, k = l >> 3;
    nIdx = k & 3;
    mIdx = xcd + 8 * (k >> 2);
    if (mIdx >= gy) return;
  } else {
    mIdx = blockIdx.x;
    nIdx = 0;
  }
  __shared__ u16 As[128 * 32];
  __shared__ u16 Bs[128 * 32];
  __shared__ float sRed[2][2][128];
  const int tid = threadIdx.x;
  const int w = tid >> 6, lane = tid & 63;
  const int wm = w >> 1, wn = w & 1;
  const int q = lane >> 4, l15 = lane & 15;
  const int nBase = nIdx * 128;
  const int mBase = mIdx * 128;
  const int h = nBase >> 7;
  const int srow = lane >> 2;
  const int skc = (lane & 3) * 8;

  f32x4 acc[4][4];
#pragma unroll
  for (int i = 0; i < 4; ++i)
#pragma unroll
    for (int j = 0; j < 4; ++j) acc[i][j] = (f32x4){0.f, 0.f, 0.f, 0.f};

  for (int k0 = 0; k0 < K; k0 += 32) {
#pragma unroll
    for (int r = 0; r < 2; ++r) {
      int lrow = w * 32 + r * 16 + srow;
      int ga = mBase + lrow;
      if (ga >= M) ga = M - 1;
      gld_lds16(A + (size_t)ga * K + k0 + skc, &As[(w * 32 + r * 16) * 32]);
      int gb = nBase + lrow;
      gld_lds16(Bt + (size_t)gb * K + k0 + skc, &Bs[(w * 32 + r * 16) * 32]);
    }
    __syncthreads();
    short8 af[4], bf[4];
#pragma unroll
    for (int i = 0; i < 4; ++i)
      af[i] = *(const short8*)&As[(wm * 64 + i * 16 + l15) * 32 + q * 8];
#pragma unroll
    for (int j = 0; j < 4; ++j)
      bf[j] = *(const short8*)&Bs[(wn * 64 + j * 16 + l15) * 32 + q * 8];
#pragma unroll
    for (int i = 0; i < 4; ++i)
#pragma unroll
      for (int j = 0; j < 4; ++j)
        acc[i][j] = __builtin_amdgcn_mfma_f32_16x16x32_bf16(af[i], bf[j], acc[i][j], 0, 0, 0);
    __syncthreads();
  }

  float asv[4], adv[4];
#pragma unroll
  for (int j = 0; j < 4; ++j) {
    int cw = wn * 64 + j * 16 + l15;
    asv[j] = a_src[h * 128 + cw];
    adv[j] = a_dst[h * 128 + cw];
  }
#pragma unroll
  for (int mi = 0; mi < 4; ++mi) {
#pragma unroll
    for (int r = 0; r < 4; ++r) {
      int row = mBase + wm * 64 + mi * 16 + q * 4 + r;
      float s = 0.f, d = 0.f;
#pragma unroll
      for (int j = 0; j < 4; ++j) {
        float v = acc[mi][j][r];
        s = fmaf(v, asv[j], s);
        d = fmaf(v, adv[j], d);
        if (row < M) Hb[(size_t)row * HC + nBase + wn * 64 + j * 16 + l15] = f2b(v);
      }
#pragma unroll
      for (int o = 8; o; o >>= 1) {
        s += __shfl_xor(s, o);
        d += __shfl_xor(d, o);
      }
      if (l15 == 0) {
        int lr = wm * 64 + mi * 16 + q * 4 + r;
        sRed[0][wn][lr] = s;
        sRed[1][wn][lr] = d;
      }
    }
  }
  __syncthreads();
  if (tid < 128) {
    int row = mBase + tid;
    if (row < M) {
      aS[(size_t)row * Hh + h] = sRed[0][0][tid] + sRed[0][1][tid];
      aD[(size_t)row * Hh + h] = sRed[1][0][tid] + sRed[1][1][tid];
    }
  }
}

// ---------------- one-pass CSR scan: single block, 1024 threads ----------------
__global__ __launch_bounds__(1024) void scan_onepass(const int* __restrict__ deg,
                                                     int* __restrict__ rowptr, int N) {
  __shared__ int ssum[1024];
  const int t = threadIdx.x;
  const int C = (N + 1023) / 1024;
  const int base = t * C;
  int s = 0;
  for (int i = 0; i < C; ++i) {
    int idx = base + i;
    if (idx < N) s += deg[idx];
  }
  ssum[t] = s;
  __syncthreads();
  for (int off = 1; off < 1024; off <<= 1) {
    int v = (t >= off) ? ssum[t - off] : 0;
    __syncthreads();
    ssum[t] += v;
    __syncthreads();
  }
  int run = (t > 0) ? ssum[t - 1] : 0;
  for (int i = 0; i < C; ++i) {
    int idx = base + i;
    if (idx < N) {
      run += deg[idx];
      rowptr[idx + 1] = run;
    }
  }
  if (t == 0) rowptr[0] = 0;
}

__global__ void csr_fill(const int* __restrict__ ei, int E0, int ET,
                         const int* __restrict__ rowptr, int* __restrict__ cnt,
                         int* __restrict__ csr_src) {
  int e = blockIdx.x * blockDim.x + threadIdx.x;
  if (e >= ET) return;
  int s, d;
  if (e < E0) { s = ei[e]; d = ei[E0 + e]; }
  else        { s = e - E0; d = e - E0; }
  int pos = atomicAdd(&cnt[d], 1);
  csr_src[rowptr[d] + pos] = s;
}

#define ACC8(pv, wgt)                                             \
  acc[0] = fmaf(wgt, b2f((u16)(pv.x & 0xffff)), acc[0]);          \
  acc[1] = fmaf(wgt, b2f((u16)(pv.x >> 16)), acc[1]);             \
  acc[2] = fmaf(wgt, b2f((u16)(pv.y & 0xffff)), acc[2]);          \
  acc[3] = fmaf(wgt, b2f((u16)(pv.y >> 16)), acc[3]);             \
  acc[4] = fmaf(wgt, b2f((u16)(pv.z & 0xffff)), acc[4]);          \
  acc[5] = fmaf(wgt, b2f((u16)(pv.z >> 16)), acc[5]);             \
  acc[6] = fmaf(wgt, b2f((u16)(pv.w & 0xffff)), acc[6]);          \
  acc[7] = fmaf(wgt, b2f((u16)(pv.w >> 16)), acc[7]);

// ---------------- fused softmax + aggregate, Hh=4: ONE WAVE PER NODE ----------------
__global__ __launch_bounds__(256) void gat_fused_agg(
    const int* __restrict__ rowptr, const int* __restrict__ csr_src,
    const u16* __restrict__ Hb, const float* __restrict__ aSb,
    const float* __restrict__ aDb, const float* __restrict__ bias,
    u16* __restrict__ outB, float* __restrict__ outF, int N) {
  const int wid = (int)((blockIdx.x * (blockDim.x >> 6)) + (threadIdx.x >> 6));
  const int lane = threadIdx.x & 63;
  if (wid >= N) return;
  const int beg = rowptr[wid];
  const int deg = rowptr[wid + 1] - beg;

  const int h = lane >> 4;
  const int e16 = lane & 15;
  const int c0 = lane * 8;
  const int hbase = lane & 48;
  const float adh = aDb[(size_t)wid * 4 + h];
  float bv[8];
  *(float4*)&bv[0] = *(const float4*)&bias[c0];
  *(float4*)&bv[4] = *(const float4*)&bias[c0 + 4];
  float m = -1e30f, ssum = 0.f;
  float acc[8] = {};
  for (int c = 0; c < deg; c += 16) {
    const int ce = min(16, deg - c);
    int srcv = 0;
    float l = -1e30f;
    if (e16 < ce) {
      srcv = csr_src[beg + c + e16];
      l = lrelu(aSb[(size_t)srcv * 4 + h] + adh);
    }
    float cm = l;
#pragma unroll
    for (int o = 8; o; o >>= 1) cm = fmaxf(cm, __shfl_xor(cm, o));
    float pexp, cs;
    if (c == 0) {
      m = cm;
      pexp = expf(l - m);
      cs = pexp;
#pragma unroll
      for (int o = 8; o; o >>= 1) cs += __shfl_xor(cs, o);
      ssum = cs;
    } else {
      float newm = fmaxf(m, cm);
      float r = expf(m - newm);
      m = newm;
      pexp = expf(l - m);
      cs = pexp;
#pragma unroll
      for (int o = 8; o; o >>= 1) cs += __shfl_xor(cs, o);
      ssum = ssum * r + cs;
#pragma unroll
      for (int i = 0; i < 8; ++i) acc[i] *= r;
    }
    int e = 0;
    for (; e + 4 <= ce; e += 4) {
      int se0 = __shfl(srcv, e + 0), se1 = __shfl(srcv, e + 1);
      int se2 = __shfl(srcv, e + 2), se3 = __shfl(srcv, e + 3);
      float w0 = __shfl(pexp, hbase | (e + 0)), w1 = __shfl(pexp, hbase | (e + 1));
      float w2 = __shfl(pexp, hbase | (e + 2)), w3 = __shfl(pexp, hbase | (e + 3));
      uint4 p0 = *(const uint4*)&Hb[(size_t)se0 * 512 + c0];
      uint4 p1 = *(const uint4*)&Hb[(size_t)se1 * 512 + c0];
      uint4 p2 = *(const uint4*)&Hb[(size_t)se2 * 512 + c0];
      uint4 p3 = *(const uint4*)&Hb[(size_t)se3 * 512 + c0];
      ACC8(p0, w0)
      ACC8(p1, w1)
      ACC8(p2, w2)
      ACC8(p3, w3)
    }
    for (; e < ce; ++e) {
      int se = __shfl(srcv, e);
      float wgt = __shfl(pexp, hbase | e);
      uint4 pv = *(const uint4*)&Hb[(size_t)se * 512 + c0];
      ACC8(pv, wgt)
    }
  }
  const float inv = 1.f / ssum;
  u16 packed[8];
#pragma unroll
  for (int i = 0; i < 8; ++i) {
    float v = fmaf(acc[i], inv, bv[i]);
    v = v > 0.f ? v : expm1f(v);
    acc[i] = v;
    packed[i] = f2b(v);
  }
  if (outB) *(uint4*)&outB[(size_t)wid * 512 + c0] = *(const uint4*)packed;
  if (outF) {
    *(float4*)&outF[(size_t)wid * 512 + c0] = make_float4(acc[0], acc[1], acc[2], acc[3]);
    *(float4*)&outF[(size_t)wid * 512 + c0 + 4] =
        make_float4(acc[4], acc[5], acc[6], acc[7]);
  }
}

// ---------------- Hh=1 aggregate: 4 edges x 16 lane-groups, 16B loads ----------------
__global__ __launch_bounds__(256) void gat_agg_h1(
    const int* __restrict__ rowptr, const int* __restrict__ csr_src,
    const u16* __restrict__ Hb, const float* __restrict__ aSb,
    const float* __restrict__ aDb, const float* __restrict__ bias,
    float* __restrict__ outF, int N) {
  const int wid = (int)((blockIdx.x * (blockDim.x >> 6)) + (threadIdx.x >> 6));
  const int lane = threadIdx.x & 63;
  if (wid >= N) return;
  const int beg = rowptr[wid];
  const int deg = rowptr[wid + 1] - beg;
  const int g = lane & 15;
  const int es = lane >> 4;
  const int c0 = g * 8;
  const float adh = aDb[wid];
  float m = -1e30f, ssum = 0.f;
  float acc[8] = {};
  for (int c = 0; c < deg; c += 64) {
    const int ce = min(64, deg - c);
    int srcv = 0;
    float l = -1e30f;
    if (lane < ce) {
      srcv = csr_src[beg + c + lane];
      l = lrelu(aSb[srcv] + adh);
    }
    float cm = l;
#pragma unroll
    for (int o = 32; o; o >>= 1) cm = fmaxf(cm, __shfl_xor(cm, o));
    float pexp, cs;
    if (c == 0) {
      m = cm;
      pexp = expf(l - m);
      cs = pexp;
#pragma unroll
      for (int o = 32; o; o >>= 1) cs += __shfl_xor(cs, o);
      ssum = cs;
    } else {
      float newm = fmaxf(m, cm);
      float r = expf(m - newm);
      m = newm;
      pexp = expf(l - m);
      cs = pexp;
#pragma unroll
      for (int o = 32; o; o >>= 1) cs += __shfl_xor(cs, o);
      ssum = ssum * r + cs;
#pragma unroll
      for (int i = 0; i < 8; ++i) acc[i] *= r;
    }
    for (int t = 0; t < ce; t += 4) {
      int idx = t + es;
      int se = __shfl(srcv, idx & 63);
      float wgt = __shfl(pexp, idx & 63);
      if (idx < ce) {
        uint4 pv = *(const uint4*)&Hb[(size_t)se * 128 + c0];
        ACC8(pv, wgt)
      }
    }
  }
#pragma unroll
  for (int i = 0; i < 8; ++i) {
    acc[i] += __shfl_xor(acc[i], 16);
    acc[i] += __shfl_xor(acc[i], 32);
  }
  if (lane < 16) {
    const float inv = 1.f / ssum;
    float o[8];
#pragma unroll
    for (int i = 0; i < 8; ++i) {
      float v = fmaf(acc[i], inv, bias[c0 + i]);
      o[i] = v > 0.f ? v : expm1f(v);
    }
    *(float4*)&outF[(size_t)wid * 128 + c0] = make_float4(o[0], o[1], o[2], o[3]);
    *(float4*)&outF[(size_t)wid * 128 + c0 + 4] = make_float4(o[4], o[5], o[6], o[7]);
  }
}

// ---------------- fused FC head ----------------
__global__ __launch_bounds__(256) void fc_head(const float* __restrict__ A,
                                               const float* __restrict__ B,
                                               const float* __restrict__ bias,
                                               const float* __restrict__ w2,
                                               const float* __restrict__ b2,
                                               float* __restrict__ out, int M) {
  __shared__ float As[16][64];
  __shared__ float Bs[16][64];
  __shared__ float sP[64][17];
  const int tid = threadIdx.x;
  const int tx = tid & 15, ty = tid >> 4;
  const int mBase = blockIdx.y * 64;
  const int aRow = tid >> 2;
  const int aK = (tid & 3) << 2;
  const int bC = tid & 63;
  const int bR0 = tid >> 6;
  const int K = 128, N = 64;
  float acc[4][4] = {};
  for (int k0 = 0; k0 < K; k0 += 16) {
    float4 av = make_float4(0.f, 0.f, 0.f, 0.f);
    int gr = mBase + aRow;
    if (gr < M) av = *(const float4*)&A[(size_t)gr * K + k0 + aK];
    As[aK + 0][aRow] = av.x;
    As[aK + 1][aRow] = av.y;
    As[aK + 2][aRow] = av.z;
    As[aK + 3][aRow] = av.w;
#pragma unroll
    for (int i = 0; i < 4; ++i) {
      int r = bR0 + i * 4;
      Bs[r][bC] = B[(size_t)(k0 + r) * N + bC];
    }
    __syncthreads();
#pragma unroll
    for (int k = 0; k < 16; ++k) {
      float4 a = *(const float4*)&As[k][ty * 4];
      float4 b = *(const float4*)&Bs[k][tx * 4];
      float ar[4] = {a.x, a.y, a.z, a.w};
      float br[4] = {b.x, b.y, b.z, b.w};
#pragma unroll
      for (int i = 0; i < 4; ++i)
#pragma unroll
        for (int j = 0; j < 4; ++j) acc[i][j] = fmaf(ar[i], br[j], acc[i][j]);
    }
    __syncthreads();
  }
  float4 bv = *(const float4*)&bias[tx * 4];
  float4 wv = *(const float4*)&w2[tx * 4];
#pragma unroll
  for (int i = 0; i < 4; ++i) {
    float p = 0.f;
    p = fmaf(fmaxf(acc[i][0] + bv.x, 0.f), wv.x, p);
    p = fmaf(fmaxf(acc[i][1] + bv.y, 0.f), wv.y, p);
    p = fmaf(fmaxf(acc[i][2] + bv.z, 0.f), wv.z, p);
    p = fmaf(fmaxf(acc[i][3] + bv.w, 0.f), wv.w, p);
    sP[ty * 4 + i][tx] = p;
  }
  __syncthreads();
  if (tid < 64) {
    int row = mBase + tid;
    if (row < M) {
      float s = 0.f;
#pragma unroll
      for (int t = 0; t < 16; ++t) s += sP[tid][t];
      out[row] = 1.f / (1.f + expf(-(s + b2[0])));
    }
  }
}

// ---------------- launch ----------------
extern "C" void kernel_launch(void* const* d_in, const int* in_sizes, int n_in,
                              void* d_out, int out_size, void* d_ws, size_t ws_size,
                              hipStream_t stream) {
  const float* x    = (const float*)d_in[0];
  const int*   ei   = (const int*)d_in[1];
  const float* W1   = (const float*)d_in[2];
  const float* as1  = (const float*)d_in[3];
  const float* ad1  = (const float*)d_in[4];
  const float* b1   = (const float*)d_in[5];
  const float* W2   = (const float*)d_in[6];
  const float* as2  = (const float*)d_in[7];
  const float* ad2  = (const float*)d_in[8];
  const float* b2   = (const float*)d_in[9];
  const float* W3   = (const float*)d_in[10];
  const float* as3  = (const float*)d_in[11];
  const float* ad3  = (const float*)d_in[12];
  const float* b3   = (const float*)d_in[13];
  const float* fc1w = (const float*)d_in[14];
  const float* fc1b = (const float*)d_in[15];
  const float* fc2w = (const float*)d_in[16];
  const float* fc2b = (const float*)d_in[17];
  float* out = (float*)d_out;

  const int N  = in_sizes[0] / 64;  // 50000
  const int E0 = in_sizes[1] / 2;   // 400000
  const int ET = E0 + N;

  char* ws = (char*)d_ws;
  size_t off = 0;
  auto alloc = [&](size_t bytes) -> void* {
    void* p = ws + off;
    off += (bytes + 255) & ~(size_t)255;
    return p;
  };
  u16*   bufXb   = (u16*)alloc((size_t)N * 512 * 2);
  u16*   bufHb   = (u16*)alloc((size_t)N * 512 * 2);
  float* bufF    = (float*)alloc((size_t)N * 128 * 4);
  float* aS      = (float*)alloc((size_t)N * 4 * 4);
  float* aD      = (float*)alloc((size_t)N * 4 * 4);
  u16*   Wt1     = (u16*)alloc((size_t)512 * 64 * 2);
  u16*   Wt2     = (u16*)alloc((size_t)512 * 512 * 2);
  u16*   Wt3     = (u16*)alloc((size_t)128 * 512 * 2);
  int*   degcnt  = (int*)alloc((size_t)2 * N * 4);
  int*   deg     = degcnt;
  int*   cnt     = degcnt + N;
  int*   rowptr  = (int*)alloc((size_t)(N + 1) * 4);
  int*   csr_src = (int*)alloc((size_t)ET * 4);
  (void)ws_size; (void)n_in; (void)out_size;

  // ---- prep: zero deg/cnt, then fused casts + degree count ----
  hipMemsetAsync(degcnt, 0, (size_t)2 * N * 4, stream);
  const int NX = N * 64;
  const int prepTotal = NX + 64 * 512 + 512 * 512 + 512 * 128 + ET;
  hipLaunchKernelGGL(fused_prep, dim3((prepTotal + 255) / 256), dim3(256), 0, stream, x,
                     bufXb, NX, W1, Wt1, W2, Wt2, W3, Wt3, ei, E0, ET, deg);

  // ---- CSR: one-pass scan (single block) + fill ----
  hipLaunchKernelGGL(scan_onepass, dim3(1), dim3(1024), 0, stream, deg, rowptr, N);
  int eb = (ET + 255) / 256;
  hipLaunchKernelGGL(csr_fill, dim3(eb), dim3(256), 0, stream, ei, E0, ET, rowptr, cnt,
                     csr_src);

  const int gy = (N + 127) / 128;                 // 391 m-tiles
  const int grid4 = ((gy + 7) / 8) * 8 * 4;       // XCD-swizzled 1-D grid for 4 strips

  // layer 1: [N,64] -> [N,512]
  hipLaunchKernelGGL(gemm_bf16_gat, dim3(grid4), dim3(256), 0, stream, bufXb, Wt1, bufHb,
                     as1, ad1, aS, aD, N, 512, 64, 4, gy, 4);
  hipLaunchKernelGGL(gat_fused_agg, dim3((N + 3) / 4), dim3(256), 0, stream, rowptr,
                     csr_src, bufHb, aS, aD, b1, bufXb, nullptr, N);
  // layer 2: [N,512] -> [N,512]
  hipLaunchKernelGGL(gemm_bf16_gat, dim3(grid4), dim3(256), 0, stream, bufXb, Wt2, bufHb,
                     as2, ad2, aS, aD, N, 512, 512, 4, gy, 4);
  hipLaunchKernelGGL(gat_fused_agg, dim3((N + 3) / 4), dim3(256), 0, stream, rowptr,
                     csr_src, bufHb, aS, aD, b2, bufXb, nullptr, N);
  // layer 3: [N,512] -> [N,128], heads=1
  hipLaunchKernelGGL(gemm_bf16_gat, dim3(gy), dim3(256), 0, stream, bufXb, Wt3, bufHb,
                     as3, ad3, aS, aD, N, 128, 512, 1, gy, 1);
  hipLaunchKernelGGL(gat_agg_h1, dim3((N + 3) / 4), dim3(256), 0, stream, rowptr, csr_src,
                     bufHb, aS, aD, b3, bufF, N);

  hipLaunchKernelGGL(fc_head, dim3(1, (N + 63) / 64), dim3(256), 0, stream, bufF, fc1w,
                     fc1b, fc2w, fc2b, out, N);
}

// Round 13
// 457.280 us; speedup vs baseline: 1.1917x; 1.1917x over previous
//
#include <hip/hip_runtime.h>
#include <math.h>

typedef __attribute__((ext_vector_type(8))) short short8;
typedef __attribute__((ext_vector_type(4))) float f32x4;
typedef unsigned short u16;
typedef unsigned int u32;

__device__ inline u16 f2b(float f) {  // f32 -> bf16 round-to-nearest-even
  u32 u = __float_as_uint(f);
  return (u16)((u + 0x7FFFu + ((u >> 16) & 1u)) >> 16);
}
__device__ inline float b2f(u16 b) { return __uint_as_float((u32)b << 16); }
__device__ inline float lrelu(float v) { return v > 0.f ? v : 0.2f * v; }

__device__ inline void gld_lds16(const void* g, void* l) {
  __builtin_amdgcn_global_load_lds((const __attribute__((address_space(1))) void*)g,
                                   (__attribute__((address_space(3))) void*)l, 16, 0, 0);
}

// ---------------- fused prep: casts (x, W1, W2, W3) + deg_count ----------------
__global__ void fused_prep(const float* __restrict__ x, u16* __restrict__ xb, int NX,
                           const float* __restrict__ W1, u16* __restrict__ Wt1,
                           const float* __restrict__ W2, u16* __restrict__ Wt2,
                           const float* __restrict__ W3, u16* __restrict__ Wt3,
                           const int* __restrict__ ei, int E0, int ET,
                           int* __restrict__ deg) {
  int i = blockIdx.x * blockDim.x + threadIdx.x;
  if (i < NX) {
    xb[i] = f2b(x[i]);
    return;
  }
  i -= NX;
  if (i < 64 * 512) {
    int k = i / 512, n = i % 512;
    Wt1[n * 64 + k] = f2b(W1[i]);
    return;
  }
  i -= 64 * 512;
  if (i < 512 * 512) {
    int k = i / 512, n = i % 512;
    Wt2[n * 512 + k] = f2b(W2[i]);
    return;
  }
  i -= 512 * 512;
  if (i < 512 * 128) {
    int k = i / 128, n = i % 128;
    Wt3[n * 512 + k] = f2b(W3[i]);
    return;
  }
  i -= 512 * 128;
  if (i < ET) {
    int d = (i < E0) ? ei[E0 + i] : (i - E0);
    atomicAdd(&deg[d], 1);
  }
}

// ---------------- bf16 MFMA GEMM with fused alpha epilogue, XCD-swizzled 1-D grid ----
// nStrips==4: linear id l -> xcd=l&7, k=l>>3, n=k&3, m=xcd+8*(k>>2); the 4 n-strips
// of an m-tile are ids spaced by 8 => same XCD => A-tile fetched once per XCD L2.
__global__ __launch_bounds__(256) void gemm_bf16_gat(
    const u16* __restrict__ A, const u16* __restrict__ Bt, u16* __restrict__ Hb,
    const float* __restrict__ a_src, const float* __restrict__ a_dst,
    float* __restrict__ aS, float* __restrict__ aD, int M, int HC, int K, int Hh,
    int gy, int nStrips) {
  int mIdx, nIdx;
  if (nStrips == 4) {
    int l = blockIdx.x;
    int xcd = l & 7, k = l >> 3;
    nIdx = k & 3;
    mIdx = xcd + 8 * (k >> 2);
    if (mIdx >= gy) return;
  } else {
    mIdx = blockIdx.x;
    nIdx = 0;
  }
  __shared__ u16 As[128 * 32];
  __shared__ u16 Bs[128 * 32];
  __shared__ float sRed[2][2][128];
  const int tid = threadIdx.x;
  const int w = tid >> 6, lane = tid & 63;
  const int wm = w >> 1, wn = w & 1;
  const int q = lane >> 4, l15 = lane & 15;
  const int nBase = nIdx * 128;
  const int mBase = mIdx * 128;
  const int h = nBase >> 7;
  const int srow = lane >> 2;
  const int skc = (lane & 3) * 8;

  f32x4 acc[4][4];
#pragma unroll
  for (int i = 0; i < 4; ++i)
#pragma unroll
    for (int j = 0; j < 4; ++j) acc[i][j] = (f32x4){0.f, 0.f, 0.f, 0.f};

  for (int k0 = 0; k0 < K; k0 += 32) {
#pragma unroll
    for (int r = 0; r < 2; ++r) {
      int lrow = w * 32 + r * 16 + srow;
      int ga = mBase + lrow;
      if (ga >= M) ga = M - 1;
      gld_lds16(A + (size_t)ga * K + k0 + skc, &As[(w * 32 + r * 16) * 32]);
      int gb = nBase + lrow;
      gld_lds16(Bt + (size_t)gb * K + k0 + skc, &Bs[(w * 32 + r * 16) * 32]);
    }
    __syncthreads();
    short8 af[4], bf[4];
#pragma unroll
    for (int i = 0; i < 4; ++i)
      af[i] = *(const short8*)&As[(wm * 64 + i * 16 + l15) * 32 + q * 8];
#pragma unroll
    for (int j = 0; j < 4; ++j)
      bf[j] = *(const short8*)&Bs[(wn * 64 + j * 16 + l15) * 32 + q * 8];
#pragma unroll
    for (int i = 0; i < 4; ++i)
#pragma unroll
      for (int j = 0; j < 4; ++j)
        acc[i][j] = __builtin_amdgcn_mfma_f32_16x16x32_bf16(af[i], bf[j], acc[i][j], 0, 0, 0);
    __syncthreads();
  }

  float asv[4], adv[4];
#pragma unroll
  for (int j = 0; j < 4; ++j) {
    int cw = wn * 64 + j * 16 + l15;
    asv[j] = a_src[h * 128 + cw];
    adv[j] = a_dst[h * 128 + cw];
  }
#pragma unroll
  for (int mi = 0; mi < 4; ++mi) {
#pragma unroll
    for (int r = 0; r < 4; ++r) {
      int row = mBase + wm * 64 + mi * 16 + q * 4 + r;
      float s = 0.f, d = 0.f;
#pragma unroll
      for (int j = 0; j < 4; ++j) {
        float v = acc[mi][j][r];
        s = fmaf(v, asv[j], s);
        d = fmaf(v, adv[j], d);
        if (row < M) Hb[(size_t)row * HC + nBase + wn * 64 + j * 16 + l15] = f2b(v);
      }
#pragma unroll
      for (int o = 8; o; o >>= 1) {
        s += __shfl_xor(s, o);
        d += __shfl_xor(d, o);
      }
      if (l15 == 0) {
        int lr = wm * 64 + mi * 16 + q * 4 + r;
        sRed[0][wn][lr] = s;
        sRed[1][wn][lr] = d;
      }
    }
  }
  __syncthreads();
  if (tid < 128) {
    int row = mBase + tid;
    if (row < M) {
      aS[(size_t)row * Hh + h] = sRed[0][0][tid] + sRed[0][1][tid];
      aD[(size_t)row * Hh + h] = sRed[1][0][tid] + sRed[1][1][tid];
    }
  }
}

// ---------------- CSR scan (5-dispatch pipeline; r9 grid.sync 40x worse, r12
// single-block scan 24x worse — multi-dispatch wins for tiny serial stages) ----
__global__ __launch_bounds__(256) void scan_chunk(const int* __restrict__ deg,
                                                  int* __restrict__ incl,
                                                  int* __restrict__ bsums, int N) {
  __shared__ int sdata[256];
  const int t = threadIdx.x;
  const int base = blockIdx.x * 2048;
  int v[8];
  int sum = 0;
#pragma unroll
  for (int i = 0; i < 8; ++i) {
    int idx = base + t * 8 + i;
    v[i] = (idx < N) ? deg[idx] : 0;
    sum += v[i];
  }
  sdata[t] = sum;
  __syncthreads();
  for (int off = 1; off < 256; off <<= 1) {
    int x = (t >= off) ? sdata[t - off] : 0;
    __syncthreads();
    sdata[t] += x;
    __syncthreads();
  }
  int run = (t > 0) ? sdata[t - 1] : 0;
#pragma unroll
  for (int i = 0; i < 8; ++i) {
    int idx = base + t * 8 + i;
    run += v[i];
    if (idx < N) incl[idx] = run;
  }
  if (t == 255) bsums[blockIdx.x] = sdata[255];
}

__global__ void scan_final(const int* __restrict__ incl, const int* __restrict__ bsums,
                           int* __restrict__ rowptr, int N, int nb) {
  int i = blockIdx.x * blockDim.x + threadIdx.x;
  if (i >= N) return;
  int chunk = i >> 11;
  int pre = 0;
  for (int j = 0; j < chunk; ++j) pre += bsums[j];
  rowptr[i + 1] = incl[i] + pre;
  if (i == 0) rowptr[0] = 0;
}

__global__ void csr_fill(const int* __restrict__ ei, int E0, int ET,
                         const int* __restrict__ rowptr, int* __restrict__ cnt,
                         int* __restrict__ csr_src) {
  int e = blockIdx.x * blockDim.x + threadIdx.x;
  if (e >= ET) return;
  int s, d;
  if (e < E0) { s = ei[e]; d = ei[E0 + e]; }
  else        { s = e - E0; d = e - E0; }
  int pos = atomicAdd(&cnt[d], 1);
  csr_src[rowptr[d] + pos] = s;
}

#define ACC8(pv, wgt)                                             \
  acc[0] = fmaf(wgt, b2f((u16)(pv.x & 0xffff)), acc[0]);          \
  acc[1] = fmaf(wgt, b2f((u16)(pv.x >> 16)), acc[1]);             \
  acc[2] = fmaf(wgt, b2f((u16)(pv.y & 0xffff)), acc[2]);          \
  acc[3] = fmaf(wgt, b2f((u16)(pv.y >> 16)), acc[3]);             \
  acc[4] = fmaf(wgt, b2f((u16)(pv.z & 0xffff)), acc[4]);          \
  acc[5] = fmaf(wgt, b2f((u16)(pv.z >> 16)), acc[5]);             \
  acc[6] = fmaf(wgt, b2f((u16)(pv.w & 0xffff)), acc[6]);          \
  acc[7] = fmaf(wgt, b2f((u16)(pv.w >> 16)), acc[7]);

// ---------------- fused softmax + aggregate, Hh=4: ONE WAVE PER NODE ----------------
__global__ __launch_bounds__(256) void gat_fused_agg(
    const int* __restrict__ rowptr, const int* __restrict__ csr_src,
    const u16* __restrict__ Hb, const float* __restrict__ aSb,
    const float* __restrict__ aDb, const float* __restrict__ bias,
    u16* __restrict__ outB, float* __restrict__ outF, int N) {
  const int wid = (int)((blockIdx.x * (blockDim.x >> 6)) + (threadIdx.x >> 6));
  const int lane = threadIdx.x & 63;
  if (wid >= N) return;
  const int beg = rowptr[wid];
  const int deg = rowptr[wid + 1] - beg;

  const int h = lane >> 4;
  const int e16 = lane & 15;
  const int c0 = lane * 8;
  const int hbase = lane & 48;
  const float adh = aDb[(size_t)wid * 4 + h];
  float bv[8];
  *(float4*)&bv[0] = *(const float4*)&bias[c0];
  *(float4*)&bv[4] = *(const float4*)&bias[c0 + 4];
  float m = -1e30f, ssum = 0.f;
  float acc[8] = {};
  for (int c = 0; c < deg; c += 16) {
    const int ce = min(16, deg - c);
    int srcv = 0;
    float l = -1e30f;
    if (e16 < ce) {
      srcv = csr_src[beg + c + e16];
      l = lrelu(aSb[(size_t)srcv * 4 + h] + adh);
    }
    float cm = l;
#pragma unroll
    for (int o = 8; o; o >>= 1) cm = fmaxf(cm, __shfl_xor(cm, o));
    float pexp, cs;
    if (c == 0) {
      m = cm;
      pexp = expf(l - m);
      cs = pexp;
#pragma unroll
      for (int o = 8; o; o >>= 1) cs += __shfl_xor(cs, o);
      ssum = cs;
    } else {
      float newm = fmaxf(m, cm);
      float r = expf(m - newm);
      m = newm;
      pexp = expf(l - m);
      cs = pexp;
#pragma unroll
      for (int o = 8; o; o >>= 1) cs += __shfl_xor(cs, o);
      ssum = ssum * r + cs;
#pragma unroll
      for (int i = 0; i < 8; ++i) acc[i] *= r;
    }
    int e = 0;
    for (; e + 4 <= ce; e += 4) {
      int se0 = __shfl(srcv, e + 0), se1 = __shfl(srcv, e + 1);
      int se2 = __shfl(srcv, e + 2), se3 = __shfl(srcv, e + 3);
      float w0 = __shfl(pexp, hbase | (e + 0)), w1 = __shfl(pexp, hbase | (e + 1));
      float w2 = __shfl(pexp, hbase | (e + 2)), w3 = __shfl(pexp, hbase | (e + 3));
      uint4 p0 = *(const uint4*)&Hb[(size_t)se0 * 512 + c0];
      uint4 p1 = *(const uint4*)&Hb[(size_t)se1 * 512 + c0];
      uint4 p2 = *(const uint4*)&Hb[(size_t)se2 * 512 + c0];
      uint4 p3 = *(const uint4*)&Hb[(size_t)se3 * 512 + c0];
      ACC8(p0, w0)
      ACC8(p1, w1)
      ACC8(p2, w2)
      ACC8(p3, w3)
    }
    for (; e < ce; ++e) {
      int se = __shfl(srcv, e);
      float wgt = __shfl(pexp, hbase | e);
      uint4 pv = *(const uint4*)&Hb[(size_t)se * 512 + c0];
      ACC8(pv, wgt)
    }
  }
  const float inv = 1.f / ssum;
  u16 packed[8];
#pragma unroll
  for (int i = 0; i < 8; ++i) {
    float v = fmaf(acc[i], inv, bv[i]);
    v = v > 0.f ? v : expm1f(v);
    acc[i] = v;
    packed[i] = f2b(v);
  }
  if (outB) *(uint4*)&outB[(size_t)wid * 512 + c0] = *(const uint4*)packed;
  if (outF) {
    *(float4*)&outF[(size_t)wid * 512 + c0] = make_float4(acc[0], acc[1], acc[2], acc[3]);
    *(float4*)&outF[(size_t)wid * 512 + c0 + 4] =
        make_float4(acc[4], acc[5], acc[6], acc[7]);
  }
}

// ---------------- Hh=1 aggregate: 4 edges x 16 lane-groups, 16B loads ----------------
__global__ __launch_bounds__(256) void gat_agg_h1(
    const int* __restrict__ rowptr, const int* __restrict__ csr_src,
    const u16* __restrict__ Hb, const float* __restrict__ aSb,
    const float* __restrict__ aDb, const float* __restrict__ bias,
    float* __restrict__ outF, int N) {
  const int wid = (int)((blockIdx.x * (blockDim.x >> 6)) + (threadIdx.x >> 6));
  const int lane = threadIdx.x & 63;
  if (wid >= N) return;
  const int beg = rowptr[wid];
  const int deg = rowptr[wid + 1] - beg;
  const int g = lane & 15;
  const int es = lane >> 4;
  const int c0 = g * 8;
  const float adh = aDb[wid];
  float m = -1e30f, ssum = 0.f;
  float acc[8] = {};
  for (int c = 0; c < deg; c += 64) {
    const int ce = min(64, deg - c);
    int srcv = 0;
    float l = -1e30f;
    if (lane < ce) {
      srcv = csr_src[beg + c + lane];
      l = lrelu(aSb[srcv] + adh);
    }
    float cm = l;
#pragma unroll
    for (int o = 32; o; o >>= 1) cm = fmaxf(cm, __shfl_xor(cm, o));
    float pexp, cs;
    if (c == 0) {
      m = cm;
      pexp = expf(l - m);
      cs = pexp;
#pragma unroll
      for (int o = 32; o; o >>= 1) cs += __shfl_xor(cs, o);
      ssum = cs;
    } else {
      float newm = fmaxf(m, cm);
      float r = expf(m - newm);
      m = newm;
      pexp = expf(l - m);
      cs = pexp;
#pragma unroll
      for (int o = 32; o; o >>= 1) cs += __shfl_xor(cs, o);
      ssum = ssum * r + cs;
#pragma unroll
      for (int i = 0; i < 8; ++i) acc[i] *= r;
    }
    for (int t = 0; t < ce; t += 4) {
      int idx = t + es;
      int se = __shfl(srcv, idx & 63);
      float wgt = __shfl(pexp, idx & 63);
      if (idx < ce) {
        uint4 pv = *(const uint4*)&Hb[(size_t)se * 128 + c0];
        ACC8(pv, wgt)
      }
    }
  }
#pragma unroll
  for (int i = 0; i < 8; ++i) {
    acc[i] += __shfl_xor(acc[i], 16);
    acc[i] += __shfl_xor(acc[i], 32);
  }
  if (lane < 16) {
    const float inv = 1.f / ssum;
    float o[8];
#pragma unroll
    for (int i = 0; i < 8; ++i) {
      float v = fmaf(acc[i], inv, bias[c0 + i]);
      o[i] = v > 0.f ? v : expm1f(v);
    }
    *(float4*)&outF[(size_t)wid * 128 + c0] = make_float4(o[0], o[1], o[2], o[3]);
    *(float4*)&outF[(size_t)wid * 128 + c0 + 4] = make_float4(o[4], o[5], o[6], o[7]);
  }
}

// ---------------- fused FC head ----------------
__global__ __launch_bounds__(256) void fc_head(const float* __restrict__ A,
                                               const float* __restrict__ B,
                                               const float* __restrict__ bias,
                                               const float* __restrict__ w2,
                                               const float* __restrict__ b2,
                                               float* __restrict__ out, int M) {
  __shared__ float As[16][64];
  __shared__ float Bs[16][64];
  __shared__ float sP[64][17];
  const int tid = threadIdx.x;
  const int tx = tid & 15, ty = tid >> 4;
  const int mBase = blockIdx.y * 64;
  const int aRow = tid >> 2;
  const int aK = (tid & 3) << 2;
  const int bC = tid & 63;
  const int bR0 = tid >> 6;
  const int K = 128, N = 64;
  float acc[4][4] = {};
  for (int k0 = 0; k0 < K; k0 += 16) {
    float4 av = make_float4(0.f, 0.f, 0.f, 0.f);
    int gr = mBase + aRow;
    if (gr < M) av = *(const float4*)&A[(size_t)gr * K + k0 + aK];
    As[aK + 0][aRow] = av.x;
    As[aK + 1][aRow] = av.y;
    As[aK + 2][aRow] = av.z;
    As[aK + 3][aRow] = av.w;
#pragma unroll
    for (int i = 0; i < 4; ++i) {
      int r = bR0 + i * 4;
      Bs[r][bC] = B[(size_t)(k0 + r) * N + bC];
    }
    __syncthreads();
#pragma unroll
    for (int k = 0; k < 16; ++k) {
      float4 a = *(const float4*)&As[k][ty * 4];
      float4 b = *(const float4*)&Bs[k][tx * 4];
      float ar[4] = {a.x, a.y, a.z, a.w};
      float br[4] = {b.x, b.y, b.z, b.w};
#pragma unroll
      for (int i = 0; i < 4; ++i)
#pragma unroll
        for (int j = 0; j < 4; ++j) acc[i][j] = fmaf(ar[i], br[j], acc[i][j]);
    }
    __syncthreads();
  }
  float4 bv = *(const float4*)&bias[tx * 4];
  float4 wv = *(const float4*)&w2[tx * 4];
#pragma unroll
  for (int i = 0; i < 4; ++i) {
    float p = 0.f;
    p = fmaf(fmaxf(acc[i][0] + bv.x, 0.f), wv.x, p);
    p = fmaf(fmaxf(acc[i][1] + bv.y, 0.f), wv.y, p);
    p = fmaf(fmaxf(acc[i][2] + bv.z, 0.f), wv.z, p);
    p = fmaf(fmaxf(acc[i][3] + bv.w, 0.f), wv.w, p);
    sP[ty * 4 + i][tx] = p;
  }
  __syncthreads();
  if (tid < 64) {
    int row = mBase + tid;
    if (row < M) {
      float s = 0.f;
#pragma unroll
      for (int t = 0; t < 16; ++t) s += sP[tid][t];
      out[row] = 1.f / (1.f + expf(-(s + b2[0])));
    }
  }
}

// ---------------- launch ----------------
extern "C" void kernel_launch(void* const* d_in, const int* in_sizes, int n_in,
                              void* d_out, int out_size, void* d_ws, size_t ws_size,
                              hipStream_t stream) {
  const float* x    = (const float*)d_in[0];
  const int*   ei   = (const int*)d_in[1];
  const float* W1   = (const float*)d_in[2];
  const float* as1  = (const float*)d_in[3];
  const float* ad1  = (const float*)d_in[4];
  const float* b1   = (const float*)d_in[5];
  const float* W2   = (const float*)d_in[6];
  const float* as2  = (const float*)d_in[7];
  const float* ad2  = (const float*)d_in[8];
  const float* b2   = (const float*)d_in[9];
  const float* W3   = (const float*)d_in[10];
  const float* as3  = (const float*)d_in[11];
  const float* ad3  = (const float*)d_in[12];
  const float* b3   = (const float*)d_in[13];
  const float* fc1w = (const float*)d_in[14];
  const float* fc1b = (const float*)d_in[15];
  const float* fc2w = (const float*)d_in[16];
  const float* fc2b = (const float*)d_in[17];
  float* out = (float*)d_out;

  const int N  = in_sizes[0] / 64;  // 50000
  const int E0 = in_sizes[1] / 2;   // 400000
  const int ET = E0 + N;

  char* ws = (char*)d_ws;
  size_t off = 0;
  auto alloc = [&](size_t bytes) -> void* {
    void* p = ws + off;
    off += (bytes + 255) & ~(size_t)255;
    return p;
  };
  u16*   bufXb   = (u16*)alloc((size_t)N * 512 * 2);
  u16*   bufHb   = (u16*)alloc((size_t)N * 512 * 2);
  float* bufF    = (float*)alloc((size_t)N * 128 * 4);
  float* aS      = (float*)alloc((size_t)N * 4 * 4);
  float* aD      = (float*)alloc((size_t)N * 4 * 4);
  u16*   Wt1     = (u16*)alloc((size_t)512 * 64 * 2);
  u16*   Wt2     = (u16*)alloc((size_t)512 * 512 * 2);
  u16*   Wt3     = (u16*)alloc((size_t)128 * 512 * 2);
  int*   degcnt  = (int*)alloc((size_t)2 * N * 4);
  int*   deg     = degcnt;
  int*   cnt     = degcnt + N;
  int*   incl    = (int*)alloc((size_t)N * 4);
  int*   rowptr  = (int*)alloc((size_t)(N + 1) * 4);
  int*   bsums   = (int*)alloc(256 * 4);
  int*   csr_src = (int*)alloc((size_t)ET * 4);
  (void)ws_size; (void)n_in; (void)out_size;

  // ---- prep: zero deg/cnt, then fused casts + degree count ----
  hipMemsetAsync(degcnt, 0, (size_t)2 * N * 4, stream);
  const int NX = N * 64;
  const int prepTotal = NX + 64 * 512 + 512 * 512 + 512 * 128 + ET;
  hipLaunchKernelGGL(fused_prep, dim3((prepTotal + 255) / 256), dim3(256), 0, stream, x,
                     bufXb, NX, W1, Wt1, W2, Wt2, W3, Wt3, ei, E0, ET, deg);

  // ---- CSR scan + fill ----
  int nb = (N + 2047) / 2048;
  hipLaunchKernelGGL(scan_chunk, dim3(nb), dim3(256), 0, stream, deg, incl, bsums, N);
  hipLaunchKernelGGL(scan_final, dim3((N + 255) / 256), dim3(256), 0, stream, incl, bsums,
                     rowptr, N, nb);
  int eb = (ET + 255) / 256;
  hipLaunchKernelGGL(csr_fill, dim3(eb), dim3(256), 0, stream, ei, E0, ET, rowptr, cnt,
                     csr_src);

  const int gy = (N + 127) / 128;                 // 391 m-tiles
  const int grid4 = ((gy + 7) / 8) * 8 * 4;       // XCD-swizzled 1-D grid for 4 strips

  // layer 1: [N,64] -> [N,512]
  hipLaunchKernelGGL(gemm_bf16_gat, dim3(grid4), dim3(256), 0, stream, bufXb, Wt1, bufHb,
                     as1, ad1, aS, aD, N, 512, 64, 4, gy, 4);
  hipLaunchKernelGGL(gat_fused_agg, dim3((N + 3) / 4), dim3(256), 0, stream, rowptr,
                     csr_src, bufHb, aS, aD, b1, bufXb, nullptr, N);
  // layer 2: [N,512] -> [N,512]
  hipLaunchKernelGGL(gemm_bf16_gat, dim3(grid4), dim3(256), 0, stream, bufXb, Wt2, bufHb,
                     as2, ad2, aS, aD, N, 512, 512, 4, gy, 4);
  hipLaunchKernelGGL(gat_fused_agg, dim3((N + 3) / 4), dim3(256), 0, stream, rowptr,
                     csr_src, bufHb, aS, aD, b2, bufXb, nullptr, N);
  // layer 3: [N,512] -> [N,128], heads=1
  hipLaunchKernelGGL(gemm_bf16_gat, dim3(gy), dim3(256), 0, stream, bufXb, Wt3, bufHb,
                     as3, ad3, aS, aD, N, 128, 512, 1, gy, 1);
  hipLaunchKernelGGL(gat_agg_h1, dim3((N + 3) / 4), dim3(256), 0, stream, rowptr, csr_src,
                     bufHb, aS, aD, b3, bufF, N);

  hipLaunchKernelGGL(fc_head, dim3(1, (N + 63) / 64), dim3(256), 0, stream, bufF, fc1w,
                     fc1b, fc2w, fc2b, out, N);
}